// Round 8
// baseline (650.888 us; speedup 1.0000x reference)
//
#include <hip/hip_runtime.h>
#include <hip/hip_bf16.h>

typedef __attribute__((ext_vector_type(4))) float f32x4;
typedef __attribute__((ext_vector_type(8))) __bf16 bfv8;
typedef __attribute__((ext_vector_type(8))) short sv8;
typedef __attribute__((ext_vector_type(4))) unsigned short usv4;

// ---------------- helpers ----------------

static __device__ __forceinline__ f32x4 mfma16(sv8 a, sv8 b, f32x4 c) {
    return __builtin_amdgcn_mfma_f32_16x16x32_bf16(
        __builtin_bit_cast(bfv8, a), __builtin_bit_cast(bfv8, b), c, 0, 0, 0);
}

static __device__ __forceinline__ unsigned short f2bf(float f) {
    union { float f; unsigned int u; } v; v.f = f;
    unsigned int u = v.u;
    return (unsigned short)((u + 0x7FFFu + ((u >> 16) & 1u)) >> 16);  // RNE
}

// async global->LDS, 16B per lane (dest linear in lane order)
static __device__ __forceinline__ void gld16(void* lds, const void* g) {
    __builtin_amdgcn_global_load_lds(
        (const __attribute__((address_space(1))) unsigned int*)g,
        (__attribute__((address_space(3))) unsigned int*)lds, 16, 0, 0);
}

// ---------------- fp32 -> bf16 convert (weights) ----------------

__global__ void cvt_bf16_kernel(const float* __restrict__ in,
                                unsigned short* __restrict__ out, int n4) {
    int i = blockIdx.x * 256 + threadIdx.x;
    if (i >= n4) return;
    float4 f = reinterpret_cast<const float4*>(in)[i];
    usv4 o = { f2bf(f.x), f2bf(f.y), f2bf(f.z), f2bf(f.w) };
    reinterpret_cast<usv4*>(out)[i] = o;
}

// ---------------- LayerNorm fp32 -> bf16, C=768 ----------------

__global__ void ln_kernel(const float* __restrict__ x, const float* __restrict__ w,
                          const float* __restrict__ b, unsigned short* __restrict__ out) {
    const int row = blockIdx.x;
    const int t = threadIdx.x;
    const float* xr = x + (size_t)row * 768;
    float v[3];
    float s = 0.f, ss = 0.f;
#pragma unroll
    for (int i = 0; i < 3; ++i) {
        v[i] = xr[t + i * 256];
        s += v[i]; ss += v[i] * v[i];
    }
#pragma unroll
    for (int o = 32; o; o >>= 1) { s += __shfl_xor(s, o); ss += __shfl_xor(ss, o); }
    __shared__ float red[8];
    if ((t & 63) == 0) { red[t >> 6] = s; red[4 + (t >> 6)] = ss; }
    __syncthreads();
    float S = red[0] + red[1] + red[2] + red[3];
    float SS = red[4] + red[5] + red[6] + red[7];
    float mu = S * (1.0f / 768.0f);
    float var = SS * (1.0f / 768.0f) - mu * mu;
    float rstd = rsqrtf(var + 1e-6f);
#pragma unroll
    for (int i = 0; i < 3; ++i) {
        int c = t + i * 256;
        out[(size_t)row * 768 + c] = f2bf((v[i] - mu) * rstd * w[c] + b[c]);
    }
}

// ---------------- prompt [B,20,2,H,64] fp32 -> K [B,H,224,64], Vt [B,H,64,224] bf16 ----------------

__global__ void prompt_kernel(const float* __restrict__ pr,
                              unsigned short* __restrict__ k_out,
                              unsigned short* __restrict__ v_out) {
    int i = blockIdx.x * 256 + threadIdx.x;  // over B*P*H*64 = 983040
    if (i >= 64 * 20 * 12 * 64) return;
    int d = i & 63;
    int t = i >> 6;
    int h = t % 12;
    int t2 = t / 12;
    int p = t2 % 20;
    int b = t2 / 20;
    size_t src = ((((size_t)b * 20 + p) * 2 + 0) * 12 + h) * 64 + d;
    float kv = pr[src];
    float vv = pr[src + 12 * 64];  // s=1 plane
    k_out[(((size_t)(b * 12 + h) * 224 + p) << 6) + d] = f2bf(kv);
    v_out[((size_t)(b * 12 + h) * 64 + d) * 224 + p] = f2bf(vv);
}

// ---------------- bf16 GEMM: C[M,N] = A[M,K] @ W[N,K]^T, fused epilogues ----------------
// Tile 128 x (NF*32), 4 waves (2x2), per-wave 64 x (NF*16) output -> NF*4 MFMA per
// wave-iter. r5-proven loop: 2-buffer LDS, stage(t+1) at iter start, one __syncthreads.
// Rationale (r8): per-iter period is structure-fixed (~3000-3400 cy, measured via fc2
// all-resident dispatch AND m97@4k cross-check); throughput = MFMA-work packed per
// period. NF=6 raises per-wave MFMA/iter 16->24 and MFMA:ds_read ratio 1.6->2.4 while
// LDS 40 KB keeps 4 blocks/CU. NF=4 == r5 exactly (control for proj/fc2).
// Grid mapping: 1-D, bijective XCD swizzle (m204), bn-fastest (r5 best-known).

#define EPI_QKV 0
#define EPI_RES 1
#define EPI_GELU 2

template <int EPI, int NF>   // NF = per-wave n-fragments; block N-tile = NF*32 (NF even)
__global__ void gemm_bf16(const unsigned short* __restrict__ A,
                          const unsigned short* __restrict__ W,
                          const float* __restrict__ bias,
                          const float* __restrict__ resid,
                          void* __restrict__ out0,
                          unsigned short* __restrict__ q_out,
                          unsigned short* __restrict__ k_out,
                          unsigned short* __restrict__ v_out,
                          int M, int N, int K, int NB) {
    constexpr int BN = NF * 32;
    __shared__ __align__(16) unsigned short As[2][128 * 32];
    __shared__ __align__(16) unsigned short Bs[2][BN * 32];
    const int tid = threadIdx.x;
    const int lane = tid & 63;
    const int wave = tid >> 6;
    const int wm = wave >> 1, wn = wave & 1;
    const int rl = lane & 15, kg = lane >> 4;

    // bijective XCD swizzle (m204); wg increases bn-fastest (bm = wg/NB)
    const int nwg = gridDim.x;
    const int orig = blockIdx.x;
    const int xcd = orig & 7;
    const int qq = nwg >> 3, rr = nwg & 7;
    const int wg = (xcd < rr ? xcd * (qq + 1) : rr * (qq + 1) + (xcd - rr) * qq) + (orig >> 3);
    const int bm = wg / NB, bn = wg - bm * NB;

    // hoisted stage base pointers (per-lane, per-chunk)
    const unsigned short* pA[2];
    const unsigned short* pB[NF / 2];
#pragma unroll
    for (int i = 0; i < 2; ++i) {
        const int c = i * 256 + tid;
        const int row = c >> 2, sl = c & 3;
        const int ss = sl ^ ((row >> 1) & 3);  // XOR swizzle (inverse on source)
        int ar = bm * 128 + row; ar = ar < M ? ar : M - 1;
        pA[i] = A + (size_t)ar * K + ss * 8;
    }
#pragma unroll
    for (int i = 0; i < NF / 2; ++i) {
        const int c = i * 256 + tid;
        const int row = c >> 2, sl = c & 3;
        const int ss = sl ^ ((row >> 1) & 3);
        pB[i] = W + (size_t)(bn * BN + row) * K + ss * 8;
    }
    auto stage = [&](int sb, int kt) {
        const int k0 = kt << 5;
#pragma unroll
        for (int i = 0; i < 2; ++i) {
            const int c = i * 256 + tid;
            gld16(&As[sb][c * 8], pA[i] + k0);
        }
#pragma unroll
        for (int i = 0; i < NF / 2; ++i) {
            const int c = i * 256 + tid;
            gld16(&Bs[sb][c * 8], pB[i] + k0);
        }
    };

    f32x4 acc[4][NF];
#pragma unroll
    for (int i = 0; i < 4; ++i)
#pragma unroll
        for (int j = 0; j < NF; ++j) acc[i][j] = f32x4{0.f, 0.f, 0.f, 0.f};

    const int nk = K >> 5;
    stage(0, 0);
    __syncthreads();
    for (int kt = 0; kt < nk; ++kt) {
        const int cur = kt & 1;
        if (kt + 1 < nk) stage(cur ^ 1, kt + 1);   // issue next-tile loads EARLY
        sv8 af[4], bfr[NF];
#pragma unroll
        for (int f = 0; f < 4; ++f) {
            const int ra = wm * 64 + f * 16 + rl;
            af[f] = *reinterpret_cast<const sv8*>(&As[cur][ra * 32 + (kg ^ ((ra >> 1) & 3)) * 8]);
        }
#pragma unroll
        for (int f = 0; f < NF; ++f) {
            const int rb = wn * (NF * 16) + f * 16 + rl;
            bfr[f] = *reinterpret_cast<const sv8*>(&Bs[cur][rb * 32 + (kg ^ ((rb >> 1) & 3)) * 8]);
        }
#pragma unroll
        for (int i = 0; i < 4; ++i)
#pragma unroll
            for (int j = 0; j < NF; ++j) acc[i][j] = mfma16(af[i], bfr[j], acc[i][j]);
        __syncthreads();   // drains vmcnt (next buf staged) + lgkm; one barrier/iter
    }

    // epilogue: C/D layout col=lane&15, row=(lane>>4)*4+reg (m89-verified)
#pragma unroll
    for (int i = 0; i < 4; ++i) {
        const int m0 = bm * 128 + wm * 64 + i * 16 + kg * 4;
#pragma unroll
        for (int j = 0; j < NF; ++j) {
            const int ncol = bn * BN + wn * (NF * 16) + j * 16 + rl;
            const float bia = bias[ncol];
#pragma unroll
            for (int r = 0; r < 4; ++r) {
                const int m = m0 + r;
                if (m >= M) continue;
                float vv = acc[i][j][r] + bia;
                if constexpr (EPI == EPI_QKV) {
                    int b = m / 197, nn = m - b * 197;
                    int which = ncol / 768;
                    int rc = ncol - which * 768;
                    int h = rc >> 6;
                    int d = ncol & 63;
                    if (which == 0)
                        q_out[(((size_t)(b * 12 + h) * 197 + nn) << 6) + d] = f2bf(vv);
                    else if (which == 1)
                        k_out[(((size_t)(b * 12 + h) * 224 + 20 + nn) << 6) + d] = f2bf(vv);
                    else
                        v_out[((size_t)(b * 12 + h) * 64 + d) * 224 + 20 + nn] = f2bf(vv);
                } else if constexpr (EPI == EPI_RES) {
                    ((float*)out0)[(size_t)m * N + ncol] = vv + resid[(size_t)m * N + ncol];
                } else {  // GELU tanh-approx in sigmoid form
                    float g = vv / (1.0f + __expf(-1.5957691216f * vv * (1.0f + 0.044715f * vv * vv)));
                    ((unsigned short*)out0)[(size_t)m * N + ncol] = f2bf(g);
                }
            }
        }
    }
}

// ---------------- attention: per (b,h,qtile64): S=QK^T, softmax, O=PV ----------------

__global__ void attn_kernel(const unsigned short* __restrict__ Qg,
                            const unsigned short* __restrict__ Kg,
                            const unsigned short* __restrict__ Vtg,
                            unsigned short* __restrict__ obuf) {
    __shared__ __align__(16) unsigned short sKS[14848];  // max(224*64, 4*16*232)
    __shared__ __align__(16) unsigned short sV[64 * 232];
    const int tid = threadIdx.x;
    const int lane = tid & 63;
    const int wave = tid >> 6;
    const int rl = lane & 15, kg = lane >> 4;
    const int qt = blockIdx.x, h = blockIdx.y, b = blockIdx.z;
    const size_t bh = (size_t)b * 12 + h;
    const size_t qbase = bh * 197 * 64;
    const size_t kbase = bh * 224 * 64;
    const size_t vbase = bh * 64 * 224;

    int qrow = qt * 64 + wave * 16 + rl;
    if (qrow > 196) qrow = 196;
    sv8 qf[2];
#pragma unroll
    for (int ks = 0; ks < 2; ++ks)
        qf[ks] = *reinterpret_cast<const sv8*>(&Qg[qbase + (size_t)qrow * 64 + ks * 32 + kg * 8]);

#pragma unroll
    for (int i = 0; i < 7; ++i) {
        const int c = i * 256 + tid;       // 1792 chunks of 16B
        const int key = c >> 3, sl = c & 7;
        const int ssl = sl ^ (key & 7);
        gld16(&sKS[c * 8], &Kg[kbase + key * 64 + ssl * 8]);
    }
#pragma unroll
    for (int i = 0; i < 7; ++i) {
        const int c = i * 256 + tid;
        const int d = c / 28, sl = c - d * 28;
        sv8 val = *reinterpret_cast<const sv8*>(&Vtg[vbase + d * 224 + sl * 8]);
        *reinterpret_cast<sv8*>(&sV[d * 232 + sl * 8]) = val;
    }
    __syncthreads();

    f32x4 sacc[14];
#pragma unroll
    for (int f = 0; f < 14; ++f) sacc[f] = f32x4{0.f, 0.f, 0.f, 0.f};
#pragma unroll
    for (int f = 0; f < 14; ++f) {
        const int key = f * 16 + rl;
#pragma unroll
        for (int ks = 0; ks < 2; ++ks) {
            const int sl = (ks * 4 + kg) ^ (key & 7);
            sv8 kf = *reinterpret_cast<const sv8*>(&sKS[key * 64 + sl * 8]);
            sacc[f] = mfma16(qf[ks], kf, sacc[f]);
        }
    }

    float mx[4] = {-1e30f, -1e30f, -1e30f, -1e30f};
#pragma unroll
    for (int f = 0; f < 14; ++f) {
        const int col = f * 16 + rl;
#pragma unroll
        for (int r = 0; r < 4; ++r) {
            float s = sacc[f][r] * 0.125f;
            if (col >= 217) s = -1e30f;
            sacc[f][r] = s;
            mx[r] = fmaxf(mx[r], s);
        }
    }
#pragma unroll
    for (int o = 1; o < 16; o <<= 1)
#pragma unroll
        for (int r = 0; r < 4; ++r) mx[r] = fmaxf(mx[r], __shfl_xor(mx[r], o));
    float sm[4] = {0.f, 0.f, 0.f, 0.f};
#pragma unroll
    for (int f = 0; f < 14; ++f)
#pragma unroll
        for (int r = 0; r < 4; ++r) {
            float e = __expf(sacc[f][r] - mx[r]);
            sacc[f][r] = e;
            sm[r] += e;
        }
#pragma unroll
    for (int o = 1; o < 16; o <<= 1)
#pragma unroll
        for (int r = 0; r < 4; ++r) sm[r] += __shfl_xor(sm[r], o);
    float inv[4];
#pragma unroll
    for (int r = 0; r < 4; ++r) inv[r] = 1.0f / sm[r];

    __syncthreads();
    unsigned short* Sl = sKS;  // S [4 waves][16 q][232]
#pragma unroll
    for (int f = 0; f < 14; ++f)
#pragma unroll
        for (int r = 0; r < 4; ++r)
            Sl[(wave * 16 + kg * 4 + r) * 232 + f * 16 + rl] = f2bf(sacc[f][r] * inv[r]);
    __syncthreads();

    f32x4 oacc[4];
#pragma unroll
    for (int fd = 0; fd < 4; ++fd) oacc[fd] = f32x4{0.f, 0.f, 0.f, 0.f};
#pragma unroll
    for (int ks = 0; ks < 7; ++ks) {
        sv8 pf = *reinterpret_cast<const sv8*>(&Sl[(wave * 16 + rl) * 232 + ks * 32 + kg * 8]);
#pragma unroll
        for (int fd = 0; fd < 4; ++fd) {
            sv8 vf = *reinterpret_cast<const sv8*>(&sV[(fd * 16 + rl) * 232 + ks * 32 + kg * 8]);
            oacc[fd] = mfma16(pf, vf, oacc[fd]);
        }
    }

#pragma unroll
    for (int fd = 0; fd < 4; ++fd)
#pragma unroll
        for (int r = 0; r < 4; ++r) {
            const int q = qt * 64 + wave * 16 + kg * 4 + r;
            if (q < 197)
                obuf[((size_t)b * 197 + q) * 768 + h * 64 + fd * 16 + rl] = f2bf(oacc[fd][r]);
        }
}

// ---------------- host ----------------

extern "C" void kernel_launch(void* const* d_in, const int* in_sizes, int n_in,
                              void* d_out, int out_size, void* d_ws, size_t ws_size,
                              hipStream_t stream) {
    const float* x      = (const float*)d_in[0];
    const float* prompt = (const float*)d_in[1];
    const float* ln1_w  = (const float*)d_in[2];
    const float* ln1_b  = (const float*)d_in[3];
    const float* qkv_w  = (const float*)d_in[4];
    const float* qkv_b  = (const float*)d_in[5];
    const float* proj_w = (const float*)d_in[6];
    const float* proj_b = (const float*)d_in[7];
    const float* ln2_w  = (const float*)d_in[8];
    const float* ln2_b  = (const float*)d_in[9];
    const float* fc1_w  = (const float*)d_in[10];
    const float* fc1_b  = (const float*)d_in[11];
    const float* fc2_w  = (const float*)d_in[12];
    const float* fc2_b  = (const float*)d_in[13];

    char* ws = (char*)d_ws;
    size_t off = 0;
    auto bump = [&](size_t bytes) {
        char* p = ws + off;
        off += (bytes + 255) & ~(size_t)255;
        return p;
    };
    unsigned short* qkvw  = (unsigned short*)bump(2304UL * 768 * 2);
    unsigned short* projw = (unsigned short*)bump(768UL * 768 * 2);
    unsigned short* fc1w  = (unsigned short*)bump(3072UL * 768 * 2);
    unsigned short* fc2w  = (unsigned short*)bump(768UL * 3072 * 2);
    unsigned short* h2    = (unsigned short*)bump(12608UL * 768 * 2);
    float* xmid           = (float*)bump(12608UL * 768 * 4);
    char* pool = ws + off;
    unsigned short* h1   = (unsigned short*)(pool);
    unsigned short* Qg   = (unsigned short*)(pool + 19365888UL);
    unsigned short* Kg   = (unsigned short*)(pool + 38731776UL);
    unsigned short* Vtg  = (unsigned short*)(pool + 60751872UL);
    unsigned short* obuf = (unsigned short*)(pool + 82771968UL);
    unsigned short* mbuf = (unsigned short*)(pool);  // aliases h1/Q/K/Vt (dead by fc1)

    cvt_bf16_kernel<<<(2304 * 768 / 4 + 255) / 256, 256, 0, stream>>>(qkv_w, qkvw, 2304 * 768 / 4);
    cvt_bf16_kernel<<<(768 * 768 / 4 + 255) / 256, 256, 0, stream>>>(proj_w, projw, 768 * 768 / 4);
    cvt_bf16_kernel<<<(3072 * 768 / 4 + 255) / 256, 256, 0, stream>>>(fc1_w, fc1w, 3072 * 768 / 4);
    cvt_bf16_kernel<<<(768 * 3072 / 4 + 255) / 256, 256, 0, stream>>>(fc2_w, fc2w, 768 * 3072 / 4);

    ln_kernel<<<12608, 256, 0, stream>>>(x, ln1_w, ln1_b, h1);
    prompt_kernel<<<983040 / 256, 256, 0, stream>>>(prompt, Kg, Vtg);

    // qkv: NF=6 (192-wide tiles): 99 x 12 blocks
    gemm_bf16<EPI_QKV, 6><<<99 * 12, 256, 0, stream>>>(
        h1, qkvw, qkv_b, nullptr, nullptr, Qg, Kg, Vtg, 12608, 2304, 768, 12);

    attn_kernel<<<dim3(4, 12, 64), 256, 0, stream>>>(Qg, Kg, Vtg, obuf);

    // proj: NF=4 (r5 control): 99 x 6
    gemm_bf16<EPI_RES, 4><<<99 * 6, 256, 0, stream>>>(
        obuf, projw, proj_b, x, xmid, nullptr, nullptr, nullptr, 12608, 768, 768, 6);

    ln_kernel<<<12608, 256, 0, stream>>>(xmid, ln2_w, ln2_b, h2);

    // fc1: NF=6: 99 x 16
    gemm_bf16<EPI_GELU, 6><<<99 * 16, 256, 0, stream>>>(
        h2, fc1w, fc1_b, nullptr, mbuf, nullptr, nullptr, nullptr, 12608, 3072, 768, 16);

    // fc2: NF=4 (r5 control): 99 x 6, K=3072
    gemm_bf16<EPI_RES, 4><<<99 * 6, 256, 0, stream>>>(
        mbuf, fc2w, fc2_b, xmid, (float*)d_out, nullptr, nullptr, nullptr, 12608, 768, 3072, 6);
}

// Round 9
// 476.283 us; speedup vs baseline: 1.3666x; 1.3666x over previous
//
#include <hip/hip_runtime.h>
#include <hip/hip_bf16.h>

typedef __attribute__((ext_vector_type(4))) float f32x4;
typedef __attribute__((ext_vector_type(8))) __bf16 bfv8;
typedef __attribute__((ext_vector_type(8))) short sv8;
typedef __attribute__((ext_vector_type(4))) unsigned short usv4;

// ---------------- helpers ----------------

static __device__ __forceinline__ f32x4 mfma16(sv8 a, sv8 b, f32x4 c) {
    return __builtin_amdgcn_mfma_f32_16x16x32_bf16(
        __builtin_bit_cast(bfv8, a), __builtin_bit_cast(bfv8, b), c, 0, 0, 0);
}

static __device__ __forceinline__ unsigned short f2bf(float f) {
    union { float f; unsigned int u; } v; v.f = f;
    unsigned int u = v.u;
    return (unsigned short)((u + 0x7FFFu + ((u >> 16) & 1u)) >> 16);  // RNE
}

// async global->LDS, 16B per lane (dest linear in lane order)
static __device__ __forceinline__ void gld16(void* lds, const void* g) {
    __builtin_amdgcn_global_load_lds(
        (const __attribute__((address_space(1))) unsigned int*)g,
        (__attribute__((address_space(3))) unsigned int*)lds, 16, 0, 0);
}

// ---------------- fp32 -> bf16 convert (weights) ----------------

__global__ void cvt_bf16_kernel(const float* __restrict__ in,
                                unsigned short* __restrict__ out, int n4) {
    int i = blockIdx.x * 256 + threadIdx.x;
    if (i >= n4) return;
    float4 f = reinterpret_cast<const float4*>(in)[i];
    usv4 o = { f2bf(f.x), f2bf(f.y), f2bf(f.z), f2bf(f.w) };
    reinterpret_cast<usv4*>(out)[i] = o;
}

// ---------------- LayerNorm fp32 -> bf16, C=768 ----------------

__global__ void ln_kernel(const float* __restrict__ x, const float* __restrict__ w,
                          const float* __restrict__ b, unsigned short* __restrict__ out) {
    const int row = blockIdx.x;
    const int t = threadIdx.x;
    const float* xr = x + (size_t)row * 768;
    float v[3];
    float s = 0.f, ss = 0.f;
#pragma unroll
    for (int i = 0; i < 3; ++i) {
        v[i] = xr[t + i * 256];
        s += v[i]; ss += v[i] * v[i];
    }
#pragma unroll
    for (int o = 32; o; o >>= 1) { s += __shfl_xor(s, o); ss += __shfl_xor(ss, o); }
    __shared__ float red[8];
    if ((t & 63) == 0) { red[t >> 6] = s; red[4 + (t >> 6)] = ss; }
    __syncthreads();
    float S = red[0] + red[1] + red[2] + red[3];
    float SS = red[4] + red[5] + red[6] + red[7];
    float mu = S * (1.0f / 768.0f);
    float var = SS * (1.0f / 768.0f) - mu * mu;
    float rstd = rsqrtf(var + 1e-6f);
#pragma unroll
    for (int i = 0; i < 3; ++i) {
        int c = t + i * 256;
        out[(size_t)row * 768 + c] = f2bf((v[i] - mu) * rstd * w[c] + b[c]);
    }
}

// ---------------- prompt [B,20,2,H,64] fp32 -> K [B,H,224,64], Vt [B,H,64,224] bf16 ----------------

__global__ void prompt_kernel(const float* __restrict__ pr,
                              unsigned short* __restrict__ k_out,
                              unsigned short* __restrict__ v_out) {
    int i = blockIdx.x * 256 + threadIdx.x;  // over B*P*H*64 = 983040
    if (i >= 64 * 20 * 12 * 64) return;
    int d = i & 63;
    int t = i >> 6;
    int h = t % 12;
    int t2 = t / 12;
    int p = t2 % 20;
    int b = t2 / 20;
    size_t src = ((((size_t)b * 20 + p) * 2 + 0) * 12 + h) * 64 + d;
    float kv = pr[src];
    float vv = pr[src + 12 * 64];  // s=1 plane
    k_out[(((size_t)(b * 12 + h) * 224 + p) << 6) + d] = f2bf(kv);
    v_out[((size_t)(b * 12 + h) * 64 + d) * 224 + p] = f2bf(vv);
}

// ---------------- bf16 GEMM: C[M,N] = A[M,K] @ W[N,K]^T, fused epilogues ----------------
// r9: BK=64 (2 MFMA k-steps per iter), 128x128 tile, 4 waves (2x2), per-wave 64x64
// output (NF=4: exact 128B-line epilogue footprint — r8 proved wider tiles cause ~4x
// HBM write amplification). r5-proven loop: 2-buffer LDS (64 KB -> 2 blocks/CU),
// stage(t+1) at iter start, one __syncthreads per iter. Halves iteration count: the
// measured ~3400 cy/iter period was structure-bound (r6 depth / r7 locality both null),
// so 2x MFMA per period should ~halve GEMM time.
// Rows are 64 elems = 8 x 16B slots; swizzle slot ^= (row&7) both-sides (attn-K pattern).
// Grid: 1-D, bijective XCD swizzle (m204), bn-fastest (r4-proven FETCH fix).

#define EPI_QKV 0
#define EPI_RES 1
#define EPI_GELU 2

template <int EPI>
__global__ void gemm_bf16(const unsigned short* __restrict__ A,
                          const unsigned short* __restrict__ W,
                          const float* __restrict__ bias,
                          const float* __restrict__ resid,
                          void* __restrict__ out0,
                          unsigned short* __restrict__ q_out,
                          unsigned short* __restrict__ k_out,
                          unsigned short* __restrict__ v_out,
                          int M, int N, int K, int NB) {
    __shared__ __align__(16) unsigned short As[2][128 * 64];
    __shared__ __align__(16) unsigned short Bs[2][128 * 64];
    const int tid = threadIdx.x;
    const int lane = tid & 63;
    const int wave = tid >> 6;
    const int wm = wave >> 1, wn = wave & 1;
    const int rl = lane & 15, kg = lane >> 4;

    // bijective XCD swizzle (m204); wg increases bn-fastest (bm = wg/NB)
    const int nwg = gridDim.x;
    const int orig = blockIdx.x;
    const int xcd = orig & 7;
    const int qq = nwg >> 3, rr = nwg & 7;
    const int wg = (xcd < rr ? xcd * (qq + 1) : rr * (qq + 1) + (xcd - rr) * qq) + (orig >> 3);
    const int bm = wg / NB, bn = wg - bm * NB;

    // hoisted stage base pointers: 1024 chunks of 16B per array, 4 per thread
    const unsigned short* pA[4];
    const unsigned short* pB[4];
#pragma unroll
    for (int i = 0; i < 4; ++i) {
        const int c = i * 256 + tid;
        const int row = c >> 3, sl = c & 7;
        const int ss = sl ^ (row & 7);        // inverse swizzle on global source
        int ar = bm * 128 + row; ar = ar < M ? ar : M - 1;
        pA[i] = A + (size_t)ar * K + ss * 8;
        pB[i] = W + (size_t)(bn * 128 + row) * K + ss * 8;
    }
    auto stage = [&](int sb, int kt) {
        const int k0 = kt << 6;
#pragma unroll
        for (int i = 0; i < 4; ++i) {
            const int c = i * 256 + tid;
            gld16(&As[sb][c * 8], pA[i] + k0);
            gld16(&Bs[sb][c * 8], pB[i] + k0);
        }
    };

    f32x4 acc[4][4];
#pragma unroll
    for (int i = 0; i < 4; ++i)
#pragma unroll
        for (int j = 0; j < 4; ++j) acc[i][j] = f32x4{0.f, 0.f, 0.f, 0.f};

    const int nk = K >> 6;
    stage(0, 0);
    __syncthreads();
    for (int kt = 0; kt < nk; ++kt) {
        const int cur = kt & 1;
        if (kt + 1 < nk) stage(cur ^ 1, kt + 1);   // issue next-tile loads EARLY
        sv8 af[4][2], bfr[4][2];
#pragma unroll
        for (int f = 0; f < 4; ++f) {
            const int ra = wm * 64 + f * 16 + rl;
            const int rb = wn * 64 + f * 16 + rl;
#pragma unroll
            for (int ks = 0; ks < 2; ++ks) {
                af[f][ks] = *reinterpret_cast<const sv8*>(
                    &As[cur][ra * 64 + (((ks << 2) | kg) ^ (ra & 7)) * 8]);
                bfr[f][ks] = *reinterpret_cast<const sv8*>(
                    &Bs[cur][rb * 64 + (((ks << 2) | kg) ^ (rb & 7)) * 8]);
            }
        }
#pragma unroll
        for (int i = 0; i < 4; ++i)
#pragma unroll
            for (int j = 0; j < 4; ++j)
#pragma unroll
                for (int ks = 0; ks < 2; ++ks)
                    acc[i][j] = mfma16(af[i][ks], bfr[j][ks], acc[i][j]);
        __syncthreads();   // drains vmcnt (next buf staged) + lgkm; one barrier/iter
    }

    // epilogue: C/D layout col=lane&15, row=(lane>>4)*4+reg (m89-verified)
#pragma unroll
    for (int i = 0; i < 4; ++i) {
        const int m0 = bm * 128 + wm * 64 + i * 16 + kg * 4;
#pragma unroll
        for (int j = 0; j < 4; ++j) {
            const int ncol = bn * 128 + wn * 64 + j * 16 + rl;
            const float bia = bias[ncol];
#pragma unroll
            for (int r = 0; r < 4; ++r) {
                const int m = m0 + r;
                if (m >= M) continue;
                float vv = acc[i][j][r] + bia;
                if constexpr (EPI == EPI_QKV) {
                    int b = m / 197, nn = m - b * 197;
                    int which = ncol / 768;
                    int rc = ncol - which * 768;
                    int h = rc >> 6;
                    int d = ncol & 63;
                    if (which == 0)
                        q_out[(((size_t)(b * 12 + h) * 197 + nn) << 6) + d] = f2bf(vv);
                    else if (which == 1)
                        k_out[(((size_t)(b * 12 + h) * 224 + 20 + nn) << 6) + d] = f2bf(vv);
                    else
                        v_out[((size_t)(b * 12 + h) * 64 + d) * 224 + 20 + nn] = f2bf(vv);
                } else if constexpr (EPI == EPI_RES) {
                    ((float*)out0)[(size_t)m * N + ncol] = vv + resid[(size_t)m * N + ncol];
                } else {  // GELU tanh-approx in sigmoid form
                    float g = vv / (1.0f + __expf(-1.5957691216f * vv * (1.0f + 0.044715f * vv * vv)));
                    ((unsigned short*)out0)[(size_t)m * N + ncol] = f2bf(g);
                }
            }
        }
    }
}

// ---------------- attention: per (b,h,qtile64): S=QK^T, softmax, O=PV ----------------

__global__ void attn_kernel(const unsigned short* __restrict__ Qg,
                            const unsigned short* __restrict__ Kg,
                            const unsigned short* __restrict__ Vtg,
                            unsigned short* __restrict__ obuf) {
    __shared__ __align__(16) unsigned short sKS[14848];  // max(224*64, 4*16*232)
    __shared__ __align__(16) unsigned short sV[64 * 232];
    const int tid = threadIdx.x;
    const int lane = tid & 63;
    const int wave = tid >> 6;
    const int rl = lane & 15, kg = lane >> 4;
    const int qt = blockIdx.x, h = blockIdx.y, b = blockIdx.z;
    const size_t bh = (size_t)b * 12 + h;
    const size_t qbase = bh * 197 * 64;
    const size_t kbase = bh * 224 * 64;
    const size_t vbase = bh * 64 * 224;

    int qrow = qt * 64 + wave * 16 + rl;
    if (qrow > 196) qrow = 196;
    sv8 qf[2];
#pragma unroll
    for (int ks = 0; ks < 2; ++ks)
        qf[ks] = *reinterpret_cast<const sv8*>(&Qg[qbase + (size_t)qrow * 64 + ks * 32 + kg * 8]);

#pragma unroll
    for (int i = 0; i < 7; ++i) {
        const int c = i * 256 + tid;       // 1792 chunks of 16B
        const int key = c >> 3, sl = c & 7;
        const int ssl = sl ^ (key & 7);
        gld16(&sKS[c * 8], &Kg[kbase + key * 64 + ssl * 8]);
    }
#pragma unroll
    for (int i = 0; i < 7; ++i) {
        const int c = i * 256 + tid;
        const int d = c / 28, sl = c - d * 28;
        sv8 val = *reinterpret_cast<const sv8*>(&Vtg[vbase + d * 224 + sl * 8]);
        *reinterpret_cast<sv8*>(&sV[d * 232 + sl * 8]) = val;
    }
    __syncthreads();

    f32x4 sacc[14];
#pragma unroll
    for (int f = 0; f < 14; ++f) sacc[f] = f32x4{0.f, 0.f, 0.f, 0.f};
#pragma unroll
    for (int f = 0; f < 14; ++f) {
        const int key = f * 16 + rl;
#pragma unroll
        for (int ks = 0; ks < 2; ++ks) {
            const int sl = (ks * 4 + kg) ^ (key & 7);
            sv8 kf = *reinterpret_cast<const sv8*>(&sKS[key * 64 + sl * 8]);
            sacc[f] = mfma16(qf[ks], kf, sacc[f]);
        }
    }

    float mx[4] = {-1e30f, -1e30f, -1e30f, -1e30f};
#pragma unroll
    for (int f = 0; f < 14; ++f) {
        const int col = f * 16 + rl;
#pragma unroll
        for (int r = 0; r < 4; ++r) {
            float s = sacc[f][r] * 0.125f;
            if (col >= 217) s = -1e30f;
            sacc[f][r] = s;
            mx[r] = fmaxf(mx[r], s);
        }
    }
#pragma unroll
    for (int o = 1; o < 16; o <<= 1)
#pragma unroll
        for (int r = 0; r < 4; ++r) mx[r] = fmaxf(mx[r], __shfl_xor(mx[r], o));
    float sm[4] = {0.f, 0.f, 0.f, 0.f};
#pragma unroll
    for (int f = 0; f < 14; ++f)
#pragma unroll
        for (int r = 0; r < 4; ++r) {
            float e = __expf(sacc[f][r] - mx[r]);
            sacc[f][r] = e;
            sm[r] += e;
        }
#pragma unroll
    for (int o = 1; o < 16; o <<= 1)
#pragma unroll
        for (int r = 0; r < 4; ++r) sm[r] += __shfl_xor(sm[r], o);
    float inv[4];
#pragma unroll
    for (int r = 0; r < 4; ++r) inv[r] = 1.0f / sm[r];

    __syncthreads();
    unsigned short* Sl = sKS;  // S [4 waves][16 q][232]
#pragma unroll
    for (int f = 0; f < 14; ++f)
#pragma unroll
        for (int r = 0; r < 4; ++r)
            Sl[(wave * 16 + kg * 4 + r) * 232 + f * 16 + rl] = f2bf(sacc[f][r] * inv[r]);
    __syncthreads();

    f32x4 oacc[4];
#pragma unroll
    for (int fd = 0; fd < 4; ++fd) oacc[fd] = f32x4{0.f, 0.f, 0.f, 0.f};
#pragma unroll
    for (int ks = 0; ks < 7; ++ks) {
        sv8 pf = *reinterpret_cast<const sv8*>(&Sl[(wave * 16 + rl) * 232 + ks * 32 + kg * 8]);
#pragma unroll
        for (int fd = 0; fd < 4; ++fd) {
            sv8 vf = *reinterpret_cast<const sv8*>(&sV[(fd * 16 + rl) * 232 + ks * 32 + kg * 8]);
            oacc[fd] = mfma16(pf, vf, oacc[fd]);
        }
    }

#pragma unroll
    for (int fd = 0; fd < 4; ++fd)
#pragma unroll
        for (int r = 0; r < 4; ++r) {
            const int q = qt * 64 + wave * 16 + kg * 4 + r;
            if (q < 197)
                obuf[((size_t)b * 197 + q) * 768 + h * 64 + fd * 16 + rl] = f2bf(oacc[fd][r]);
        }
}

// ---------------- host ----------------

extern "C" void kernel_launch(void* const* d_in, const int* in_sizes, int n_in,
                              void* d_out, int out_size, void* d_ws, size_t ws_size,
                              hipStream_t stream) {
    const float* x      = (const float*)d_in[0];
    const float* prompt = (const float*)d_in[1];
    const float* ln1_w  = (const float*)d_in[2];
    const float* ln1_b  = (const float*)d_in[3];
    const float* qkv_w  = (const float*)d_in[4];
    const float* qkv_b  = (const float*)d_in[5];
    const float* proj_w = (const float*)d_in[6];
    const float* proj_b = (const float*)d_in[7];
    const float* ln2_w  = (const float*)d_in[8];
    const float* ln2_b  = (const float*)d_in[9];
    const float* fc1_w  = (const float*)d_in[10];
    const float* fc1_b  = (const float*)d_in[11];
    const float* fc2_w  = (const float*)d_in[12];
    const float* fc2_b  = (const float*)d_in[13];

    char* ws = (char*)d_ws;
    size_t off = 0;
    auto bump = [&](size_t bytes) {
        char* p = ws + off;
        off += (bytes + 255) & ~(size_t)255;
        return p;
    };
    unsigned short* qkvw  = (unsigned short*)bump(2304UL * 768 * 2);
    unsigned short* projw = (unsigned short*)bump(768UL * 768 * 2);
    unsigned short* fc1w  = (unsigned short*)bump(3072UL * 768 * 2);
    unsigned short* fc2w  = (unsigned short*)bump(768UL * 3072 * 2);
    unsigned short* h2    = (unsigned short*)bump(12608UL * 768 * 2);
    float* xmid           = (float*)bump(12608UL * 768 * 4);
    char* pool = ws + off;
    unsigned short* h1   = (unsigned short*)(pool);
    unsigned short* Qg   = (unsigned short*)(pool + 19365888UL);
    unsigned short* Kg   = (unsigned short*)(pool + 38731776UL);
    unsigned short* Vtg  = (unsigned short*)(pool + 60751872UL);
    unsigned short* obuf = (unsigned short*)(pool + 82771968UL);
    unsigned short* mbuf = (unsigned short*)(pool);  // aliases h1/Q/K/Vt (dead by fc1)

    cvt_bf16_kernel<<<(2304 * 768 / 4 + 255) / 256, 256, 0, stream>>>(qkv_w, qkvw, 2304 * 768 / 4);
    cvt_bf16_kernel<<<(768 * 768 / 4 + 255) / 256, 256, 0, stream>>>(proj_w, projw, 768 * 768 / 4);
    cvt_bf16_kernel<<<(3072 * 768 / 4 + 255) / 256, 256, 0, stream>>>(fc1_w, fc1w, 3072 * 768 / 4);
    cvt_bf16_kernel<<<(768 * 3072 / 4 + 255) / 256, 256, 0, stream>>>(fc2_w, fc2w, 768 * 3072 / 4);

    ln_kernel<<<12608, 256, 0, stream>>>(x, ln1_w, ln1_b, h1);
    prompt_kernel<<<983040 / 256, 256, 0, stream>>>(prompt, Kg, Vtg);

    // qkv: 99 m-blocks x 18 n-blocks, K=768 (12 iters)
    gemm_bf16<EPI_QKV><<<99 * 18, 256, 0, stream>>>(
        h1, qkvw, qkv_b, nullptr, nullptr, Qg, Kg, Vtg, 12608, 2304, 768, 18);

    attn_kernel<<<dim3(4, 12, 64), 256, 0, stream>>>(Qg, Kg, Vtg, obuf);

    // proj: 99 x 6, K=768
    gemm_bf16<EPI_RES><<<99 * 6, 256, 0, stream>>>(
        obuf, projw, proj_b, x, xmid, nullptr, nullptr, nullptr, 12608, 768, 768, 6);

    ln_kernel<<<12608, 256, 0, stream>>>(xmid, ln2_w, ln2_b, h2);

    // fc1: 99 x 24, K=768
    gemm_bf16<EPI_GELU><<<99 * 24, 256, 0, stream>>>(
        h2, fc1w, fc1_b, nullptr, mbuf, nullptr, nullptr, nullptr, 12608, 3072, 768, 24);

    // fc2: 99 x 6, K=3072 (48 iters)
    gemm_bf16<EPI_RES><<<99 * 6, 256, 0, stream>>>(
        mbuf, fc2w, fc2_b, xmid, (float*)d_out, nullptr, nullptr, nullptr, 12608, 768, 3072, 6);
}

// Round 10
// 425.355 us; speedup vs baseline: 1.5302x; 1.1197x over previous
//
#include <hip/hip_runtime.h>
#include <hip/hip_bf16.h>

typedef __attribute__((ext_vector_type(4))) float f32x4;
typedef __attribute__((ext_vector_type(8))) __bf16 bfv8;
typedef __attribute__((ext_vector_type(8))) short sv8;
typedef __attribute__((ext_vector_type(4))) unsigned short usv4;

// ---------------- helpers ----------------

static __device__ __forceinline__ f32x4 mfma16(sv8 a, sv8 b, f32x4 c) {
    return __builtin_amdgcn_mfma_f32_16x16x32_bf16(
        __builtin_bit_cast(bfv8, a), __builtin_bit_cast(bfv8, b), c, 0, 0, 0);
}

static __device__ __forceinline__ unsigned short f2bf(float f) {
    union { float f; unsigned int u; } v; v.f = f;
    unsigned int u = v.u;
    return (unsigned short)((u + 0x7FFFu + ((u >> 16) & 1u)) >> 16);  // RNE
}

// async global->LDS, 16B per lane (dest linear in lane order)
static __device__ __forceinline__ void gld16(void* lds, const void* g) {
    __builtin_amdgcn_global_load_lds(
        (const __attribute__((address_space(1))) unsigned int*)g,
        (__attribute__((address_space(3))) unsigned int*)lds, 16, 0, 0);
}

// ---------------- fp32 -> bf16 convert (weights) ----------------

__global__ void cvt_bf16_kernel(const float* __restrict__ in,
                                unsigned short* __restrict__ out, int n4) {
    int i = blockIdx.x * 256 + threadIdx.x;
    if (i >= n4) return;
    float4 f = reinterpret_cast<const float4*>(in)[i];
    usv4 o = { f2bf(f.x), f2bf(f.y), f2bf(f.z), f2bf(f.w) };
    reinterpret_cast<usv4*>(out)[i] = o;
}

// ---------------- LayerNorm fp32 -> bf16, C=768 ----------------

__global__ void ln_kernel(const float* __restrict__ x, const float* __restrict__ w,
                          const float* __restrict__ b, unsigned short* __restrict__ out) {
    const int row = blockIdx.x;
    const int t = threadIdx.x;
    const float* xr = x + (size_t)row * 768;
    float v[3];
    float s = 0.f, ss = 0.f;
#pragma unroll
    for (int i = 0; i < 3; ++i) {
        v[i] = xr[t + i * 256];
        s += v[i]; ss += v[i] * v[i];
    }
#pragma unroll
    for (int o = 32; o; o >>= 1) { s += __shfl_xor(s, o); ss += __shfl_xor(ss, o); }
    __shared__ float red[8];
    if ((t & 63) == 0) { red[t >> 6] = s; red[4 + (t >> 6)] = ss; }
    __syncthreads();
    float S = red[0] + red[1] + red[2] + red[3];
    float SS = red[4] + red[5] + red[6] + red[7];
    float mu = S * (1.0f / 768.0f);
    float var = SS * (1.0f / 768.0f) - mu * mu;
    float rstd = rsqrtf(var + 1e-6f);
#pragma unroll
    for (int i = 0; i < 3; ++i) {
        int c = t + i * 256;
        out[(size_t)row * 768 + c] = f2bf((v[i] - mu) * rstd * w[c] + b[c]);
    }
}

// ---------------- prompt [B,20,2,H,64] fp32 -> K [B,H,224,64], Vt [B,H,64,224] bf16 ----------------

__global__ void prompt_kernel(const float* __restrict__ pr,
                              unsigned short* __restrict__ k_out,
                              unsigned short* __restrict__ v_out) {
    int i = blockIdx.x * 256 + threadIdx.x;  // over B*P*H*64 = 983040
    if (i >= 64 * 20 * 12 * 64) return;
    int d = i & 63;
    int t = i >> 6;
    int h = t % 12;
    int t2 = t / 12;
    int p = t2 % 20;
    int b = t2 / 20;
    size_t src = ((((size_t)b * 20 + p) * 2 + 0) * 12 + h) * 64 + d;
    float kv = pr[src];
    float vv = pr[src + 12 * 64];  // s=1 plane
    k_out[(((size_t)(b * 12 + h) * 224 + p) << 6) + d] = f2bf(kv);
    v_out[((size_t)(b * 12 + h) * 64 + d) * 224 + p] = f2bf(vv);
}

// ---------------- bf16 GEMM: C[M,N] = A[M,K] @ W[N,K]^T, fused epilogues ----------------
// r10: r5's proven body (128x128, BK=32, 4 waves, 2-buffer LDS, stage-early + one
// __syncthreads per iter) with the XOR swizzle REMOVED from the staging path.
// Diagnosis (r2-r9 invariant): per-CU slot per 16KB-staged block-iter = ~1480cy across
// all occupancy/depth/BK/L2 variants, vs m97's 736cy for the identical structure. The
// only shared difference: our global_load_lds SOURCE was XOR-permuted (inverse swizzle),
// so consecutive lanes read 16B granules out of order within each 64B row -> coalescer
// can't form full-line requests -> ~4x L2/L3 sector transactions -> staging-rate
// collapse (~10 B/cy/CU vs m97's 19.5). Linear source restores coalescing; we accept
// the m97-style 8-way ds_read_b128 bank conflict (~190cy/wave-iter, overlappable).
// Grid: 1-D, bijective XCD swizzle (m204), bn-fastest (r4-proven FETCH fix).

#define EPI_QKV 0
#define EPI_RES 1
#define EPI_GELU 2

template <int EPI>
__global__ void gemm_bf16(const unsigned short* __restrict__ A,
                          const unsigned short* __restrict__ W,
                          const float* __restrict__ bias,
                          const float* __restrict__ resid,
                          void* __restrict__ out0,
                          unsigned short* __restrict__ q_out,
                          unsigned short* __restrict__ k_out,
                          unsigned short* __restrict__ v_out,
                          int M, int N, int K, int NB) {
    __shared__ __align__(16) unsigned short As[2][128 * 32];
    __shared__ __align__(16) unsigned short Bs[2][128 * 32];
    const int tid = threadIdx.x;
    const int lane = tid & 63;
    const int wave = tid >> 6;
    const int wm = wave >> 1, wn = wave & 1;
    const int rl = lane & 15, kg = lane >> 4;

    // bijective XCD swizzle (m204); wg increases bn-fastest (bm = wg/NB)
    const int nwg = gridDim.x;
    const int orig = blockIdx.x;
    const int xcd = orig & 7;
    const int qq = nwg >> 3, rr = nwg & 7;
    const int wg = (xcd < rr ? xcd * (qq + 1) : rr * (qq + 1) + (xcd - rr) * qq) + (orig >> 3);
    const int bm = wg / NB, bn = wg - bm * NB;

    // hoisted stage base pointers (LINEAR source: consecutive lanes -> consecutive 16B)
    const unsigned short* pA[2];
    const unsigned short* pB[2];
#pragma unroll
    for (int i = 0; i < 2; ++i) {
        const int c = i * 256 + tid;
        const int row = c >> 2, sl = c & 3;
        int ar = bm * 128 + row; ar = ar < M ? ar : M - 1;
        pA[i] = A + (size_t)ar * K + sl * 8;
        pB[i] = W + (size_t)(bn * 128 + row) * K + sl * 8;
    }
    auto stage = [&](int sb, int kt) {
        const int k0 = kt << 5;
#pragma unroll
        for (int i = 0; i < 2; ++i) {
            const int c = i * 256 + tid;
            gld16(&As[sb][c * 8], pA[i] + k0);
            gld16(&Bs[sb][c * 8], pB[i] + k0);
        }
    };

    f32x4 acc[4][4];
#pragma unroll
    for (int i = 0; i < 4; ++i)
#pragma unroll
        for (int j = 0; j < 4; ++j) acc[i][j] = f32x4{0.f, 0.f, 0.f, 0.f};

    const int nk = K >> 5;
    stage(0, 0);
    __syncthreads();
    for (int kt = 0; kt < nk; ++kt) {
        const int cur = kt & 1;
        if (kt + 1 < nk) stage(cur ^ 1, kt + 1);   // issue next-tile loads EARLY
        sv8 af[4], bfr[4];
#pragma unroll
        for (int f = 0; f < 4; ++f) {
            const int ra = wm * 64 + f * 16 + rl;
            af[f] = *reinterpret_cast<const sv8*>(&As[cur][ra * 32 + kg * 8]);
            const int rb = wn * 64 + f * 16 + rl;
            bfr[f] = *reinterpret_cast<const sv8*>(&Bs[cur][rb * 32 + kg * 8]);
        }
#pragma unroll
        for (int i = 0; i < 4; ++i)
#pragma unroll
            for (int j = 0; j < 4; ++j) acc[i][j] = mfma16(af[i], bfr[j], acc[i][j]);
        __syncthreads();   // drains vmcnt (next buf staged) + lgkm; one barrier/iter
    }

    // epilogue: C/D layout col=lane&15, row=(lane>>4)*4+reg (m89-verified)
#pragma unroll
    for (int i = 0; i < 4; ++i) {
        const int m0 = bm * 128 + wm * 64 + i * 16 + kg * 4;
#pragma unroll
        for (int j = 0; j < 4; ++j) {
            const int ncol = bn * 128 + wn * 64 + j * 16 + rl;
            const float bia = bias[ncol];
#pragma unroll
            for (int r = 0; r < 4; ++r) {
                const int m = m0 + r;
                if (m >= M) continue;
                float vv = acc[i][j][r] + bia;
                if constexpr (EPI == EPI_QKV) {
                    int b = m / 197, nn = m - b * 197;
                    int which = ncol / 768;
                    int rc = ncol - which * 768;
                    int h = rc >> 6;
                    int d = ncol & 63;
                    if (which == 0)
                        q_out[(((size_t)(b * 12 + h) * 197 + nn) << 6) + d] = f2bf(vv);
                    else if (which == 1)
                        k_out[(((size_t)(b * 12 + h) * 224 + 20 + nn) << 6) + d] = f2bf(vv);
                    else
                        v_out[((size_t)(b * 12 + h) * 64 + d) * 224 + 20 + nn] = f2bf(vv);
                } else if constexpr (EPI == EPI_RES) {
                    ((float*)out0)[(size_t)m * N + ncol] = vv + resid[(size_t)m * N + ncol];
                } else {  // GELU tanh-approx in sigmoid form
                    float g = vv / (1.0f + __expf(-1.5957691216f * vv * (1.0f + 0.044715f * vv * vv)));
                    ((unsigned short*)out0)[(size_t)m * N + ncol] = f2bf(g);
                }
            }
        }
    }
}

// ---------------- attention: per (b,h,qtile64): S=QK^T, softmax, O=PV ----------------

__global__ void attn_kernel(const unsigned short* __restrict__ Qg,
                            const unsigned short* __restrict__ Kg,
                            const unsigned short* __restrict__ Vtg,
                            unsigned short* __restrict__ obuf) {
    __shared__ __align__(16) unsigned short sKS[14848];  // max(224*64, 4*16*232)
    __shared__ __align__(16) unsigned short sV[64 * 232];
    const int tid = threadIdx.x;
    const int lane = tid & 63;
    const int wave = tid >> 6;
    const int rl = lane & 15, kg = lane >> 4;
    const int qt = blockIdx.x, h = blockIdx.y, b = blockIdx.z;
    const size_t bh = (size_t)b * 12 + h;
    const size_t qbase = bh * 197 * 64;
    const size_t kbase = bh * 224 * 64;
    const size_t vbase = bh * 64 * 224;

    int qrow = qt * 64 + wave * 16 + rl;
    if (qrow > 196) qrow = 196;
    sv8 qf[2];
#pragma unroll
    for (int ks = 0; ks < 2; ++ks)
        qf[ks] = *reinterpret_cast<const sv8*>(&Qg[qbase + (size_t)qrow * 64 + ks * 32 + kg * 8]);

#pragma unroll
    for (int i = 0; i < 7; ++i) {
        const int c = i * 256 + tid;       // 1792 chunks of 16B
        const int key = c >> 3, sl = c & 7;
        const int ssl = sl ^ (key & 7);
        gld16(&sKS[c * 8], &Kg[kbase + key * 64 + ssl * 8]);
    }
#pragma unroll
    for (int i = 0; i < 7; ++i) {
        const int c = i * 256 + tid;
        const int d = c / 28, sl = c - d * 28;
        sv8 val = *reinterpret_cast<const sv8*>(&Vtg[vbase + d * 224 + sl * 8]);
        *reinterpret_cast<sv8*>(&sV[d * 232 + sl * 8]) = val;
    }
    __syncthreads();

    f32x4 sacc[14];
#pragma unroll
    for (int f = 0; f < 14; ++f) sacc[f] = f32x4{0.f, 0.f, 0.f, 0.f};
#pragma unroll
    for (int f = 0; f < 14; ++f) {
        const int key = f * 16 + rl;
#pragma unroll
        for (int ks = 0; ks < 2; ++ks) {
            const int sl = (ks * 4 + kg) ^ (key & 7);
            sv8 kf = *reinterpret_cast<const sv8*>(&sKS[key * 64 + sl * 8]);
            sacc[f] = mfma16(qf[ks], kf, sacc[f]);
        }
    }

    float mx[4] = {-1e30f, -1e30f, -1e30f, -1e30f};
#pragma unroll
    for (int f = 0; f < 14; ++f) {
        const int col = f * 16 + rl;
#pragma unroll
        for (int r = 0; r < 4; ++r) {
            float s = sacc[f][r] * 0.125f;
            if (col >= 217) s = -1e30f;
            sacc[f][r] = s;
            mx[r] = fmaxf(mx[r], s);
        }
    }
#pragma unroll
    for (int o = 1; o < 16; o <<= 1)
#pragma unroll
        for (int r = 0; r < 4; ++r) mx[r] = fmaxf(mx[r], __shfl_xor(mx[r], o));
    float sm[4] = {0.f, 0.f, 0.f, 0.f};
#pragma unroll
    for (int f = 0; f < 14; ++f)
#pragma unroll
        for (int r = 0; r < 4; ++r) {
            float e = __expf(sacc[f][r] - mx[r]);
            sacc[f][r] = e;
            sm[r] += e;
        }
#pragma unroll
    for (int o = 1; o < 16; o <<= 1)
#pragma unroll
        for (int r = 0; r < 4; ++r) sm[r] += __shfl_xor(sm[r], o);
    float inv[4];
#pragma unroll
    for (int r = 0; r < 4; ++r) inv[r] = 1.0f / sm[r];

    __syncthreads();
    unsigned short* Sl = sKS;  // S [4 waves][16 q][232]
#pragma unroll
    for (int f = 0; f < 14; ++f)
#pragma unroll
        for (int r = 0; r < 4; ++r)
            Sl[(wave * 16 + kg * 4 + r) * 232 + f * 16 + rl] = f2bf(sacc[f][r] * inv[r]);
    __syncthreads();

    f32x4 oacc[4];
#pragma unroll
    for (int fd = 0; fd < 4; ++fd) oacc[fd] = f32x4{0.f, 0.f, 0.f, 0.f};
#pragma unroll
    for (int ks = 0; ks < 7; ++ks) {
        sv8 pf = *reinterpret_cast<const sv8*>(&Sl[(wave * 16 + rl) * 232 + ks * 32 + kg * 8]);
#pragma unroll
        for (int fd = 0; fd < 4; ++fd) {
            sv8 vf = *reinterpret_cast<const sv8*>(&sV[(fd * 16 + rl) * 232 + ks * 32 + kg * 8]);
            oacc[fd] = mfma16(pf, vf, oacc[fd]);
        }
    }

#pragma unroll
    for (int fd = 0; fd < 4; ++fd)
#pragma unroll
        for (int r = 0; r < 4; ++r) {
            const int q = qt * 64 + wave * 16 + kg * 4 + r;
            if (q < 197)
                obuf[((size_t)b * 197 + q) * 768 + h * 64 + fd * 16 + rl] = f2bf(oacc[fd][r]);
        }
}

// ---------------- host ----------------

extern "C" void kernel_launch(void* const* d_in, const int* in_sizes, int n_in,
                              void* d_out, int out_size, void* d_ws, size_t ws_size,
                              hipStream_t stream) {
    const float* x      = (const float*)d_in[0];
    const float* prompt = (const float*)d_in[1];
    const float* ln1_w  = (const float*)d_in[2];
    const float* ln1_b  = (const float*)d_in[3];
    const float* qkv_w  = (const float*)d_in[4];
    const float* qkv_b  = (const float*)d_in[5];
    const float* proj_w = (const float*)d_in[6];
    const float* proj_b = (const float*)d_in[7];
    const float* ln2_w  = (const float*)d_in[8];
    const float* ln2_b  = (const float*)d_in[9];
    const float* fc1_w  = (const float*)d_in[10];
    const float* fc1_b  = (const float*)d_in[11];
    const float* fc2_w  = (const float*)d_in[12];
    const float* fc2_b  = (const float*)d_in[13];

    char* ws = (char*)d_ws;
    size_t off = 0;
    auto bump = [&](size_t bytes) {
        char* p = ws + off;
        off += (bytes + 255) & ~(size_t)255;
        return p;
    };
    unsigned short* qkvw  = (unsigned short*)bump(2304UL * 768 * 2);
    unsigned short* projw = (unsigned short*)bump(768UL * 768 * 2);
    unsigned short* fc1w  = (unsigned short*)bump(3072UL * 768 * 2);
    unsigned short* fc2w  = (unsigned short*)bump(768UL * 3072 * 2);
    unsigned short* h2    = (unsigned short*)bump(12608UL * 768 * 2);
    float* xmid           = (float*)bump(12608UL * 768 * 4);
    char* pool = ws + off;
    unsigned short* h1   = (unsigned short*)(pool);
    unsigned short* Qg   = (unsigned short*)(pool + 19365888UL);
    unsigned short* Kg   = (unsigned short*)(pool + 38731776UL);
    unsigned short* Vtg  = (unsigned short*)(pool + 60751872UL);
    unsigned short* obuf = (unsigned short*)(pool + 82771968UL);
    unsigned short* mbuf = (unsigned short*)(pool);  // aliases h1/Q/K/Vt (dead by fc1)

    cvt_bf16_kernel<<<(2304 * 768 / 4 + 255) / 256, 256, 0, stream>>>(qkv_w, qkvw, 2304 * 768 / 4);
    cvt_bf16_kernel<<<(768 * 768 / 4 + 255) / 256, 256, 0, stream>>>(proj_w, projw, 768 * 768 / 4);
    cvt_bf16_kernel<<<(3072 * 768 / 4 + 255) / 256, 256, 0, stream>>>(fc1_w, fc1w, 3072 * 768 / 4);
    cvt_bf16_kernel<<<(768 * 3072 / 4 + 255) / 256, 256, 0, stream>>>(fc2_w, fc2w, 768 * 3072 / 4);

    ln_kernel<<<12608, 256, 0, stream>>>(x, ln1_w, ln1_b, h1);
    prompt_kernel<<<983040 / 256, 256, 0, stream>>>(prompt, Kg, Vtg);

    // qkv: 99 m-blocks x 18 n-blocks
    gemm_bf16<EPI_QKV><<<99 * 18, 256, 0, stream>>>(
        h1, qkvw, qkv_b, nullptr, nullptr, Qg, Kg, Vtg, 12608, 2304, 768, 18);

    attn_kernel<<<dim3(4, 12, 64), 256, 0, stream>>>(Qg, Kg, Vtg, obuf);

    // proj: 99 x 6
    gemm_bf16<EPI_RES><<<99 * 6, 256, 0, stream>>>(
        obuf, projw, proj_b, x, xmid, nullptr, nullptr, nullptr, 12608, 768, 768, 6);

    ln_kernel<<<12608, 256, 0, stream>>>(xmid, ln2_w, ln2_b, h2);

    // fc1: 99 x 24
    gemm_bf16<EPI_GELU><<<99 * 24, 256, 0, stream>>>(
        h2, fc1w, fc1_b, nullptr, mbuf, nullptr, nullptr, nullptr, 12608, 3072, 768, 24);

    // fc2: 99 x 6, K=3072
    gemm_bf16<EPI_RES><<<99 * 6, 256, 0, stream>>>(
        mbuf, fc2w, fc2_b, xmid, (float*)d_out, nullptr, nullptr, nullptr, 12608, 768, 3072, 6);
}

// Round 11
// 417.871 us; speedup vs baseline: 1.5576x; 1.0179x over previous
//
#include <hip/hip_runtime.h>
#include <hip/hip_bf16.h>

typedef __attribute__((ext_vector_type(4))) float f32x4;
typedef __attribute__((ext_vector_type(8))) __bf16 bfv8;
typedef __attribute__((ext_vector_type(8))) short sv8;
typedef __attribute__((ext_vector_type(4))) unsigned short usv4;

// ---------------- helpers ----------------

static __device__ __forceinline__ f32x4 mfma16(sv8 a, sv8 b, f32x4 c) {
    return __builtin_amdgcn_mfma_f32_16x16x32_bf16(
        __builtin_bit_cast(bfv8, a), __builtin_bit_cast(bfv8, b), c, 0, 0, 0);
}

static __device__ __forceinline__ unsigned short f2bf(float f) {
    union { float f; unsigned int u; } v; v.f = f;
    unsigned int u = v.u;
    return (unsigned short)((u + 0x7FFFu + ((u >> 16) & 1u)) >> 16);  // RNE
}

// async global->LDS, 16B per lane (dest linear in lane order)
static __device__ __forceinline__ void gld16(void* lds, const void* g) {
    __builtin_amdgcn_global_load_lds(
        (const __attribute__((address_space(1))) unsigned int*)g,
        (__attribute__((address_space(3))) unsigned int*)lds, 16, 0, 0);
}

// ---------------- fp32 -> bf16 convert (weights) ----------------

__global__ void cvt_bf16_kernel(const float* __restrict__ in,
                                unsigned short* __restrict__ out, int n4) {
    int i = blockIdx.x * 256 + threadIdx.x;
    if (i >= n4) return;
    float4 f = reinterpret_cast<const float4*>(in)[i];
    usv4 o = { f2bf(f.x), f2bf(f.y), f2bf(f.z), f2bf(f.w) };
    reinterpret_cast<usv4*>(out)[i] = o;
}

// ---------------- LayerNorm fp32 -> bf16, C=768 ----------------

__global__ void ln_kernel(const float* __restrict__ x, const float* __restrict__ w,
                          const float* __restrict__ b, unsigned short* __restrict__ out) {
    const int row = blockIdx.x;
    const int t = threadIdx.x;
    const float* xr = x + (size_t)row * 768;
    float v[3];
    float s = 0.f, ss = 0.f;
#pragma unroll
    for (int i = 0; i < 3; ++i) {
        v[i] = xr[t + i * 256];
        s += v[i]; ss += v[i] * v[i];
    }
#pragma unroll
    for (int o = 32; o; o >>= 1) { s += __shfl_xor(s, o); ss += __shfl_xor(ss, o); }
    __shared__ float red[8];
    if ((t & 63) == 0) { red[t >> 6] = s; red[4 + (t >> 6)] = ss; }
    __syncthreads();
    float S = red[0] + red[1] + red[2] + red[3];
    float SS = red[4] + red[5] + red[6] + red[7];
    float mu = S * (1.0f / 768.0f);
    float var = SS * (1.0f / 768.0f) - mu * mu;
    float rstd = rsqrtf(var + 1e-6f);
#pragma unroll
    for (int i = 0; i < 3; ++i) {
        int c = t + i * 256;
        out[(size_t)row * 768 + c] = f2bf((v[i] - mu) * rstd * w[c] + b[c]);
    }
}

// ---------------- prompt [B,20,2,H,64] fp32 -> K [B,H,224,64], Vt [B,H,64,224] bf16 ----------------

__global__ void prompt_kernel(const float* __restrict__ pr,
                              unsigned short* __restrict__ k_out,
                              unsigned short* __restrict__ v_out) {
    int i = blockIdx.x * 256 + threadIdx.x;  // over B*P*H*64 = 983040
    if (i >= 64 * 20 * 12 * 64) return;
    int d = i & 63;
    int t = i >> 6;
    int h = t % 12;
    int t2 = t / 12;
    int p = t2 % 20;
    int b = t2 / 20;
    size_t src = ((((size_t)b * 20 + p) * 2 + 0) * 12 + h) * 64 + d;
    float kv = pr[src];
    float vv = pr[src + 12 * 64];  // s=1 plane
    k_out[(((size_t)(b * 12 + h) * 224 + p) << 6) + d] = f2bf(kv);
    v_out[((size_t)(b * 12 + h) * 64 + d) * 224 + p] = f2bf(vv);
}

// ---------------- bf16 GEMM: C[M,N] = A[M,K] @ W[N,K]^T, fused epilogues ----------------
// r11: taller M-tile. Template WM = waves along M; tile = (WM*64) x 128, WM*2 waves
// (WMx2), 64x64 per wave (identical per-wave registers/epilogue-footprint to r5 -> no
// VGPR cliff, no write amplification). Evidence (r2-r10 invariant): per-CU cost per
// staged block-iter is ~constant; so reduce staged bytes per output FLOP (prop to
// 1/BM + 1/BN) and halve block-iteration count. WM=4 for qkv/fc1 (LDS 48KB, 2-3
// blk/CU); WM=2 == r10 exactly for proj/fc2 (controls).
// Loop = r5/r10 proven: 2-buffer LDS, stage(t+1) at iter start, one __syncthreads/iter.
// Linear staging (r10: swizzle/bank-conflicts measurably irrelevant).
// Grid: 1-D, bijective XCD swizzle (m204), bn-fastest (r4-proven FETCH fix).

#define EPI_QKV 0
#define EPI_RES 1
#define EPI_GELU 2

template <int EPI, int WM>
__global__ void gemm_bf16(const unsigned short* __restrict__ A,
                          const unsigned short* __restrict__ W,
                          const float* __restrict__ bias,
                          const float* __restrict__ resid,
                          void* __restrict__ out0,
                          unsigned short* __restrict__ q_out,
                          unsigned short* __restrict__ k_out,
                          unsigned short* __restrict__ v_out,
                          int M, int N, int K, int NB) {
    constexpr int THREADS = WM * 128;     // WM*2 waves
    constexpr int BM = WM * 64;
    constexpr int BCH = 512 / THREADS;    // B-stage chunks per thread (128*4/THREADS)
    __shared__ __align__(16) unsigned short As[2][BM * 32];
    __shared__ __align__(16) unsigned short Bs[2][128 * 32];
    const int tid = threadIdx.x;
    const int lane = tid & 63;
    const int wave = tid >> 6;
    const int wm = wave >> 1, wn = wave & 1;
    const int rl = lane & 15, kg = lane >> 4;

    // bijective XCD swizzle (m204); wg increases bn-fastest (bm = wg/NB)
    const int nwg = gridDim.x;
    const int orig = blockIdx.x;
    const int xcd = orig & 7;
    const int qq = nwg >> 3, rr = nwg & 7;
    const int wg = (xcd < rr ? xcd * (qq + 1) : rr * (qq + 1) + (xcd - rr) * qq) + (orig >> 3);
    const int bm = wg / NB, bn = wg - bm * NB;

    // hoisted stage base pointers (linear source)
    const unsigned short* pA[2];
    const unsigned short* pB[BCH];
#pragma unroll
    for (int i = 0; i < 2; ++i) {
        const int c = i * THREADS + tid;   // over BM*4 chunks
        const int row = c >> 2, sl = c & 3;
        int ar = bm * BM + row; ar = ar < M ? ar : M - 1;
        pA[i] = A + (size_t)ar * K + sl * 8;
    }
#pragma unroll
    for (int i = 0; i < BCH; ++i) {
        const int c = i * THREADS + tid;   // over 512 chunks
        const int row = c >> 2, sl = c & 3;
        pB[i] = W + (size_t)(bn * 128 + row) * K + sl * 8;
    }
    auto stage = [&](int sb, int kt) {
        const int k0 = kt << 5;
#pragma unroll
        for (int i = 0; i < 2; ++i) {
            const int c = i * THREADS + tid;
            gld16(&As[sb][c * 8], pA[i] + k0);
        }
#pragma unroll
        for (int i = 0; i < BCH; ++i) {
            const int c = i * THREADS + tid;
            gld16(&Bs[sb][c * 8], pB[i] + k0);
        }
    };

    f32x4 acc[4][4];
#pragma unroll
    for (int i = 0; i < 4; ++i)
#pragma unroll
        for (int j = 0; j < 4; ++j) acc[i][j] = f32x4{0.f, 0.f, 0.f, 0.f};

    const int nk = K >> 5;
    stage(0, 0);
    __syncthreads();
    for (int kt = 0; kt < nk; ++kt) {
        const int cur = kt & 1;
        if (kt + 1 < nk) stage(cur ^ 1, kt + 1);   // issue next-tile loads EARLY
        sv8 af[4], bfr[4];
#pragma unroll
        for (int f = 0; f < 4; ++f) {
            const int ra = wm * 64 + f * 16 + rl;
            af[f] = *reinterpret_cast<const sv8*>(&As[cur][ra * 32 + kg * 8]);
            const int rb = wn * 64 + f * 16 + rl;
            bfr[f] = *reinterpret_cast<const sv8*>(&Bs[cur][rb * 32 + kg * 8]);
        }
#pragma unroll
        for (int i = 0; i < 4; ++i)
#pragma unroll
            for (int j = 0; j < 4; ++j) acc[i][j] = mfma16(af[i], bfr[j], acc[i][j]);
        __syncthreads();   // drains vmcnt (next buf staged) + lgkm; one barrier/iter
    }

    // epilogue: C/D layout col=lane&15, row=(lane>>4)*4+reg (m89-verified)
#pragma unroll
    for (int i = 0; i < 4; ++i) {
        const int m0 = bm * BM + wm * 64 + i * 16 + kg * 4;
#pragma unroll
        for (int j = 0; j < 4; ++j) {
            const int ncol = bn * 128 + wn * 64 + j * 16 + rl;
            const float bia = bias[ncol];
#pragma unroll
            for (int r = 0; r < 4; ++r) {
                const int m = m0 + r;
                if (m >= M) continue;
                float vv = acc[i][j][r] + bia;
                if constexpr (EPI == EPI_QKV) {
                    int b = m / 197, nn = m - b * 197;
                    int which = ncol / 768;
                    int rc = ncol - which * 768;
                    int h = rc >> 6;
                    int d = ncol & 63;
                    if (which == 0)
                        q_out[(((size_t)(b * 12 + h) * 197 + nn) << 6) + d] = f2bf(vv);
                    else if (which == 1)
                        k_out[(((size_t)(b * 12 + h) * 224 + 20 + nn) << 6) + d] = f2bf(vv);
                    else
                        v_out[((size_t)(b * 12 + h) * 64 + d) * 224 + 20 + nn] = f2bf(vv);
                } else if constexpr (EPI == EPI_RES) {
                    ((float*)out0)[(size_t)m * N + ncol] = vv + resid[(size_t)m * N + ncol];
                } else {  // GELU tanh-approx in sigmoid form
                    float g = vv / (1.0f + __expf(-1.5957691216f * vv * (1.0f + 0.044715f * vv * vv)));
                    ((unsigned short*)out0)[(size_t)m * N + ncol] = f2bf(g);
                }
            }
        }
    }
}

// ---------------- attention: per (b,h,qtile64): S=QK^T, softmax, O=PV ----------------

__global__ void attn_kernel(const unsigned short* __restrict__ Qg,
                            const unsigned short* __restrict__ Kg,
                            const unsigned short* __restrict__ Vtg,
                            unsigned short* __restrict__ obuf) {
    __shared__ __align__(16) unsigned short sKS[14848];  // max(224*64, 4*16*232)
    __shared__ __align__(16) unsigned short sV[64 * 232];
    const int tid = threadIdx.x;
    const int lane = tid & 63;
    const int wave = tid >> 6;
    const int rl = lane & 15, kg = lane >> 4;
    const int qt = blockIdx.x, h = blockIdx.y, b = blockIdx.z;
    const size_t bh = (size_t)b * 12 + h;
    const size_t qbase = bh * 197 * 64;
    const size_t kbase = bh * 224 * 64;
    const size_t vbase = bh * 64 * 224;

    int qrow = qt * 64 + wave * 16 + rl;
    if (qrow > 196) qrow = 196;
    sv8 qf[2];
#pragma unroll
    for (int ks = 0; ks < 2; ++ks)
        qf[ks] = *reinterpret_cast<const sv8*>(&Qg[qbase + (size_t)qrow * 64 + ks * 32 + kg * 8]);

#pragma unroll
    for (int i = 0; i < 7; ++i) {
        const int c = i * 256 + tid;       // 1792 chunks of 16B
        const int key = c >> 3, sl = c & 7;
        const int ssl = sl ^ (key & 7);
        gld16(&sKS[c * 8], &Kg[kbase + key * 64 + ssl * 8]);
    }
#pragma unroll
    for (int i = 0; i < 7; ++i) {
        const int c = i * 256 + tid;
        const int d = c / 28, sl = c - d * 28;
        sv8 val = *reinterpret_cast<const sv8*>(&Vtg[vbase + d * 224 + sl * 8]);
        *reinterpret_cast<sv8*>(&sV[d * 232 + sl * 8]) = val;
    }
    __syncthreads();

    f32x4 sacc[14];
#pragma unroll
    for (int f = 0; f < 14; ++f) sacc[f] = f32x4{0.f, 0.f, 0.f, 0.f};
#pragma unroll
    for (int f = 0; f < 14; ++f) {
        const int key = f * 16 + rl;
#pragma unroll
        for (int ks = 0; ks < 2; ++ks) {
            const int sl = (ks * 4 + kg) ^ (key & 7);
            sv8 kf = *reinterpret_cast<const sv8*>(&sKS[key * 64 + sl * 8]);
            sacc[f] = mfma16(qf[ks], kf, sacc[f]);
        }
    }

    float mx[4] = {-1e30f, -1e30f, -1e30f, -1e30f};
#pragma unroll
    for (int f = 0; f < 14; ++f) {
        const int col = f * 16 + rl;
#pragma unroll
        for (int r = 0; r < 4; ++r) {
            float s = sacc[f][r] * 0.125f;
            if (col >= 217) s = -1e30f;
            sacc[f][r] = s;
            mx[r] = fmaxf(mx[r], s);
        }
    }
#pragma unroll
    for (int o = 1; o < 16; o <<= 1)
#pragma unroll
        for (int r = 0; r < 4; ++r) mx[r] = fmaxf(mx[r], __shfl_xor(mx[r], o));
    float sm[4] = {0.f, 0.f, 0.f, 0.f};
#pragma unroll
    for (int f = 0; f < 14; ++f)
#pragma unroll
        for (int r = 0; r < 4; ++r) {
            float e = __expf(sacc[f][r] - mx[r]);
            sacc[f][r] = e;
            sm[r] += e;
        }
#pragma unroll
    for (int o = 1; o < 16; o <<= 1)
#pragma unroll
        for (int r = 0; r < 4; ++r) sm[r] += __shfl_xor(sm[r], o);
    float inv[4];
#pragma unroll
    for (int r = 0; r < 4; ++r) inv[r] = 1.0f / sm[r];

    __syncthreads();
    unsigned short* Sl = sKS;  // S [4 waves][16 q][232]
#pragma unroll
    for (int f = 0; f < 14; ++f)
#pragma unroll
        for (int r = 0; r < 4; ++r)
            Sl[(wave * 16 + kg * 4 + r) * 232 + f * 16 + rl] = f2bf(sacc[f][r] * inv[r]);
    __syncthreads();

    f32x4 oacc[4];
#pragma unroll
    for (int fd = 0; fd < 4; ++fd) oacc[fd] = f32x4{0.f, 0.f, 0.f, 0.f};
#pragma unroll
    for (int ks = 0; ks < 7; ++ks) {
        sv8 pf = *reinterpret_cast<const sv8*>(&Sl[(wave * 16 + rl) * 232 + ks * 32 + kg * 8]);
#pragma unroll
        for (int fd = 0; fd < 4; ++fd) {
            sv8 vf = *reinterpret_cast<const sv8*>(&sV[(fd * 16 + rl) * 232 + ks * 32 + kg * 8]);
            oacc[fd] = mfma16(pf, vf, oacc[fd]);
        }
    }

#pragma unroll
    for (int fd = 0; fd < 4; ++fd)
#pragma unroll
        for (int r = 0; r < 4; ++r) {
            const int q = qt * 64 + wave * 16 + kg * 4 + r;
            if (q < 197)
                obuf[((size_t)b * 197 + q) * 768 + h * 64 + fd * 16 + rl] = f2bf(oacc[fd][r]);
        }
}

// ---------------- host ----------------

extern "C" void kernel_launch(void* const* d_in, const int* in_sizes, int n_in,
                              void* d_out, int out_size, void* d_ws, size_t ws_size,
                              hipStream_t stream) {
    const float* x      = (const float*)d_in[0];
    const float* prompt = (const float*)d_in[1];
    const float* ln1_w  = (const float*)d_in[2];
    const float* ln1_b  = (const float*)d_in[3];
    const float* qkv_w  = (const float*)d_in[4];
    const float* qkv_b  = (const float*)d_in[5];
    const float* proj_w = (const float*)d_in[6];
    const float* proj_b = (const float*)d_in[7];
    const float* ln2_w  = (const float*)d_in[8];
    const float* ln2_b  = (const float*)d_in[9];
    const float* fc1_w  = (const float*)d_in[10];
    const float* fc1_b  = (const float*)d_in[11];
    const float* fc2_w  = (const float*)d_in[12];
    const float* fc2_b  = (const float*)d_in[13];

    char* ws = (char*)d_ws;
    size_t off = 0;
    auto bump = [&](size_t bytes) {
        char* p = ws + off;
        off += (bytes + 255) & ~(size_t)255;
        return p;
    };
    unsigned short* qkvw  = (unsigned short*)bump(2304UL * 768 * 2);
    unsigned short* projw = (unsigned short*)bump(768UL * 768 * 2);
    unsigned short* fc1w  = (unsigned short*)bump(3072UL * 768 * 2);
    unsigned short* fc2w  = (unsigned short*)bump(768UL * 3072 * 2);
    unsigned short* h2    = (unsigned short*)bump(12608UL * 768 * 2);
    float* xmid           = (float*)bump(12608UL * 768 * 4);
    char* pool = ws + off;
    unsigned short* h1   = (unsigned short*)(pool);
    unsigned short* Qg   = (unsigned short*)(pool + 19365888UL);
    unsigned short* Kg   = (unsigned short*)(pool + 38731776UL);
    unsigned short* Vtg  = (unsigned short*)(pool + 60751872UL);
    unsigned short* obuf = (unsigned short*)(pool + 82771968UL);
    unsigned short* mbuf = (unsigned short*)(pool);  // aliases h1/Q/K/Vt (dead by fc1)

    cvt_bf16_kernel<<<(2304 * 768 / 4 + 255) / 256, 256, 0, stream>>>(qkv_w, qkvw, 2304 * 768 / 4);
    cvt_bf16_kernel<<<(768 * 768 / 4 + 255) / 256, 256, 0, stream>>>(proj_w, projw, 768 * 768 / 4);
    cvt_bf16_kernel<<<(3072 * 768 / 4 + 255) / 256, 256, 0, stream>>>(fc1_w, fc1w, 3072 * 768 / 4);
    cvt_bf16_kernel<<<(768 * 3072 / 4 + 255) / 256, 256, 0, stream>>>(fc2_w, fc2w, 768 * 3072 / 4);

    ln_kernel<<<12608, 256, 0, stream>>>(x, ln1_w, ln1_b, h1);
    prompt_kernel<<<983040 / 256, 256, 0, stream>>>(prompt, Kg, Vtg);

    // qkv: WM=4 (256x128 tiles): 50 x 18 blocks, 512 threads
    gemm_bf16<EPI_QKV, 4><<<50 * 18, 512, 0, stream>>>(
        h1, qkvw, qkv_b, nullptr, nullptr, Qg, Kg, Vtg, 12608, 2304, 768, 18);

    attn_kernel<<<dim3(4, 12, 64), 256, 0, stream>>>(Qg, Kg, Vtg, obuf);

    // proj: WM=2 (r10 control): 99 x 6
    gemm_bf16<EPI_RES, 2><<<99 * 6, 256, 0, stream>>>(
        obuf, projw, proj_b, x, xmid, nullptr, nullptr, nullptr, 12608, 768, 768, 6);

    ln_kernel<<<12608, 256, 0, stream>>>(xmid, ln2_w, ln2_b, h2);

    // fc1: WM=4: 50 x 24 blocks, 512 threads
    gemm_bf16<EPI_GELU, 4><<<50 * 24, 512, 0, stream>>>(
        h2, fc1w, fc1_b, nullptr, mbuf, nullptr, nullptr, nullptr, 12608, 3072, 768, 24);

    // fc2: WM=2 (r10 control): 99 x 6, K=3072
    gemm_bf16<EPI_RES, 2><<<99 * 6, 256, 0, stream>>>(
        mbuf, fc2w, fc2_b, xmid, (float*)d_out, nullptr, nullptr, nullptr, 12608, 768, 3072, 6);
}